// Round 5
// baseline (1014.719 us; speedup 1.0000x reference)
//
#include <hip/hip_runtime.h>
#include <hip/hip_bf16.h>

#define NN 50000
#define NE 800000
#define BN_EPS 1e-5f
#define CHUNK 4096
#define NCH 196    // ceil(NE / CHUNK)
#define NBK 196    // ceil(NN / 256) dst-buckets
#define GRID 768   // 3 blocks/CU; launch_bounds(256,4) guarantees co-residency
#define NGRP 782   // ceil(NN/64) node-groups for GEMM-shaped phases
#define NPREP 3326 // prep virtual blocks: 196 hist + 3125 cvt + 5 weights

typedef __attribute__((ext_vector_type(4))) float f32x4;
typedef __attribute__((ext_vector_type(8))) short s16x8;   // 8 bf16 = MFMA A/B frag
typedef __attribute__((ext_vector_type(4))) short s16x4;

__device__ __forceinline__ float bs2f(short v) {
    unsigned u = ((unsigned)(unsigned short)v) << 16;
    return __builtin_bit_cast(float, u);
}
__device__ __forceinline__ short f2bs(float v) {
    __hip_bfloat16 b = __float2bfloat16(v);
    return __builtin_bit_cast(short, b);
}

struct Params {
    const int* src; const int* dst;
    const float* x;
    const float *w0a, *b0a, *g0a, *be0a, *w0b, *b0b, *g0b, *be0b;
    const float *w1a, *b1a, *g1a, *be1a, *w1b, *b1b, *g1b, *be1b;
    const float *lw, *lb;
    float* out;
    int* part; float* sums; int* bbase; int* bres; int* off; int* adj; int* ebuf;
    short* Xb; short* HCb; float* T; float* T2;
    short *Wt0a, *Wt0b, *Wt1a, *Wt1b, *Wtf;
    unsigned* bar;   // 16 barrier slots, memset to 0 before each launch
};

// ---- software grid barrier (all GRID blocks co-resident by launch_bounds) -----
// release: syncthreads drained stores (compiler emits waitcnt before s_barrier);
// agent-scope RMW release flushes L2; acquire threadfence invalidates L1/L2.
__device__ __forceinline__ void gbar(unsigned* bar, int idx) {
    __syncthreads();
    if (threadIdx.x == 0) {
        __threadfence();
        __hip_atomic_fetch_add(&bar[idx], 1u, __ATOMIC_RELEASE, __HIP_MEMORY_SCOPE_AGENT);
        while (__hip_atomic_load(&bar[idx], __ATOMIC_RELAXED, __HIP_MEMORY_SCOPE_AGENT)
               < (unsigned)GRID) {
            __builtin_amdgcn_s_sleep(2);
        }
        __threadfence();
    }
    __syncthreads();
}

// ---- gather + MFMA GEMM + bias + BN stats (R1-verified body) ------------------
__device__ __forceinline__ void ggemm_phase(int blk, const short* Xp,
        const int* __restrict__ off, const int* __restrict__ adj,
        const short* __restrict__ Wt, const float* __restrict__ bias,
        float* __restrict__ T, float* __restrict__ sums, float* smf) {
    float* lsum = smf; float* lssq = smf + 64;
    int t = threadIdx.x;
    if (t < 64) { lsum[t] = 0.f; lssq[t] = 0.f; }
    __syncthreads();
    int wv = t >> 6, L = t & 63;
    int m = L & 15, quad = L >> 4;
    int wrow = blk * 64 + wv * 16;
    int node = wrow + m;
    if (node >= NN) node = NN - 1;  // dup row; stores/stats guarded below

    const short* rp = Xp + (size_t)node * 64 + quad * 8;
    s16x8 sl = *(const s16x8*)rp;
    s16x8 shh = *(const s16x8*)(rp + 32);
    float aL[8], aH[8];
    #pragma unroll
    for (int j = 0; j < 8; j++) { aL[j] = bs2f(sl[j]); aH[j] = bs2f(shh[j]); }

    int s = off[node], e = off[node + 1];
    int p = s;
    for (; p + 8 <= e; p += 8) {
        int jx[8];
        #pragma unroll
        for (int q = 0; q < 8; q++) jx[q] = adj[p + q];
        s16x8 v[8], w[8];
        #pragma unroll
        for (int q = 0; q < 8; q++) {
            const short* r = Xp + (size_t)jx[q] * 64 + quad * 8;
            v[q] = *(const s16x8*)r;
            w[q] = *(const s16x8*)(r + 32);
        }
        #pragma unroll
        for (int j = 0; j < 8; j++) {
            float sv = ((bs2f(v[0][j]) + bs2f(v[1][j])) + (bs2f(v[2][j]) + bs2f(v[3][j])))
                     + ((bs2f(v[4][j]) + bs2f(v[5][j])) + (bs2f(v[6][j]) + bs2f(v[7][j])));
            float sw = ((bs2f(w[0][j]) + bs2f(w[1][j])) + (bs2f(w[2][j]) + bs2f(w[3][j])))
                     + ((bs2f(w[4][j]) + bs2f(w[5][j])) + (bs2f(w[6][j]) + bs2f(w[7][j])));
            aL[j] += sv;
            aH[j] += sw;
        }
    }
    if (p + 4 <= e) {
        int j0 = adj[p], j1 = adj[p + 1], j2 = adj[p + 2], j3 = adj[p + 3];
        const short* r0 = Xp + (size_t)j0 * 64 + quad * 8;
        const short* r1 = Xp + (size_t)j1 * 64 + quad * 8;
        const short* r2 = Xp + (size_t)j2 * 64 + quad * 8;
        const short* r3 = Xp + (size_t)j3 * 64 + quad * 8;
        s16x8 v0 = *(const s16x8*)r0, w0 = *(const s16x8*)(r0 + 32);
        s16x8 v1 = *(const s16x8*)r1, w1 = *(const s16x8*)(r1 + 32);
        s16x8 v2 = *(const s16x8*)r2, w2 = *(const s16x8*)(r2 + 32);
        s16x8 v3 = *(const s16x8*)r3, w3 = *(const s16x8*)(r3 + 32);
        #pragma unroll
        for (int j = 0; j < 8; j++) {
            aL[j] += (bs2f(v0[j]) + bs2f(v1[j])) + (bs2f(v2[j]) + bs2f(v3[j]));
            aH[j] += (bs2f(w0[j]) + bs2f(w1[j])) + (bs2f(w2[j]) + bs2f(w3[j]));
        }
        p += 4;
    }
    for (; p < e; p++) {
        int j0 = adj[p];
        const short* r0 = Xp + (size_t)j0 * 64 + quad * 8;
        s16x8 v0 = *(const s16x8*)r0, w0 = *(const s16x8*)(r0 + 32);
        #pragma unroll
        for (int j = 0; j < 8; j++) { aL[j] += bs2f(v0[j]); aH[j] += bs2f(w0[j]); }
    }

    s16x8 a0, a1;
    #pragma unroll
    for (int j = 0; j < 8; j++) { a0[j] = f2bs(aL[j]); a1[j] = f2bs(aH[j]); }

    f32x4 acc[4];
    #pragma unroll
    for (int nt = 0; nt < 4; nt++) {
        int n = nt * 16 + m;
        s16x8 b0 = *(const s16x8*)(Wt + n * 64 + quad * 8);
        s16x8 b1 = *(const s16x8*)(Wt + n * 64 + 32 + quad * 8);
        acc[nt] = (f32x4){0.f, 0.f, 0.f, 0.f};
        acc[nt] = __builtin_amdgcn_mfma_f32_16x16x32_bf16(a0, b0, acc[nt], 0, 0, 0);
        acc[nt] = __builtin_amdgcn_mfma_f32_16x16x32_bf16(a1, b1, acc[nt], 0, 0, 0);
    }
    #pragma unroll
    for (int nt = 0; nt < 4; nt++) {
        int col = nt * 16 + m;
        float bv = bias[col];
        float ps = 0.f, pq = 0.f;
        #pragma unroll
        for (int r = 0; r < 4; r++) {
            int orow = wrow + quad * 4 + r;
            if (orow < NN) {
                float v = acc[nt][r] + bv;
                T[(size_t)orow * 64 + col] = v;
                ps += v;
                pq += v * v;
            }
        }
        atomicAdd(&lsum[col], ps);
        atomicAdd(&lssq[col], pq);
    }
    __syncthreads();
    if (t < 64) {
        atomicAdd(&sums[t], lsum[t]);
        atomicAdd(&sums[64 + t], lssq[t]);
    }
}

// ---- GEMM with A = relu(bn(Tin)) on the fly -> T + stats ----------------------
__device__ __forceinline__ void gemmbn_phase(int blk, const float* __restrict__ Tin,
        const float* __restrict__ stats,
        const float* __restrict__ g, const float* __restrict__ be,
        const short* __restrict__ Wt, const float* __restrict__ bias,
        float* __restrict__ T, float* __restrict__ sums, float* smf) {
    float* sc = smf; float* sh = smf + 64;
    float* lsum = smf + 128; float* lssq = smf + 192;
    int tid = threadIdx.x;
    if (tid < 64) {
        float mm = stats[tid] * (1.0f / NN);
        float var = stats[64 + tid] * (1.0f / NN) - mm * mm;
        if (var < 0.f) var = 0.f;
        float s = g[tid] * rsqrtf(var + BN_EPS);
        sc[tid] = s;
        sh[tid] = be[tid] - mm * s;
        lsum[tid] = 0.f; lssq[tid] = 0.f;
    }
    __syncthreads();
    int wv = tid >> 6, L = tid & 63;
    int m = L & 15, quad = L >> 4;
    int wrow = blk * 64 + wv * 16;
    int arow = wrow + m;
    if (arow >= NN) arow = NN - 1;
    f32x4 t0 = *(const f32x4*)(Tin + (size_t)arow * 64 + quad * 8);
    f32x4 t1 = *(const f32x4*)(Tin + (size_t)arow * 64 + quad * 8 + 4);
    f32x4 t2 = *(const f32x4*)(Tin + (size_t)arow * 64 + 32 + quad * 8);
    f32x4 t3 = *(const f32x4*)(Tin + (size_t)arow * 64 + 32 + quad * 8 + 4);
    s16x8 a0, a1;
    #pragma unroll
    for (int j = 0; j < 4; j++) {
        int k0 = quad * 8 + j, k1 = quad * 8 + 4 + j;
        float u0 = t0[j] * sc[k0] + sh[k0]; a0[j]     = f2bs(u0 > 0.f ? u0 : 0.f);
        float u1 = t1[j] * sc[k1] + sh[k1]; a0[4 + j] = f2bs(u1 > 0.f ? u1 : 0.f);
        float u2 = t2[j] * sc[32 + k0] + sh[32 + k0]; a1[j]     = f2bs(u2 > 0.f ? u2 : 0.f);
        float u3 = t3[j] * sc[32 + k1] + sh[32 + k1]; a1[4 + j] = f2bs(u3 > 0.f ? u3 : 0.f);
    }
    f32x4 acc[4];
    #pragma unroll
    for (int nt = 0; nt < 4; nt++) {
        int n = nt * 16 + m;
        s16x8 b0 = *(const s16x8*)(Wt + n * 64 + quad * 8);
        s16x8 b1 = *(const s16x8*)(Wt + n * 64 + 32 + quad * 8);
        acc[nt] = (f32x4){0.f, 0.f, 0.f, 0.f};
        acc[nt] = __builtin_amdgcn_mfma_f32_16x16x32_bf16(a0, b0, acc[nt], 0, 0, 0);
        acc[nt] = __builtin_amdgcn_mfma_f32_16x16x32_bf16(a1, b1, acc[nt], 0, 0, 0);
    }
    #pragma unroll
    for (int nt = 0; nt < 4; nt++) {
        int col = nt * 16 + m;
        float bv = bias[col];
        float ps = 0.f, pq = 0.f;
        #pragma unroll
        for (int r = 0; r < 4; r++) {
            int orow = wrow + quad * 4 + r;
            if (orow < NN) {
                float v = acc[nt][r] + bv;
                T[(size_t)orow * 64 + col] = v;
                ps += v;
                pq += v * v;
            }
        }
        atomicAdd(&lsum[col], ps);
        atomicAdd(&lssq[col], pq);
    }
    __syncthreads();
    if (tid < 64) {
        atomicAdd(&sums[tid], lsum[tid]);
        atomicAdd(&sums[64 + tid], lssq[tid]);
    }
}

// ---- BN finalize + apply + ReLU: T fp32 -> Hb bf16 (grid-stride) --------------
__device__ __forceinline__ void bn_phase(const float* __restrict__ T,
        const float* __restrict__ sums,
        const float* __restrict__ g, const float* __restrict__ be,
        short* __restrict__ Hb, float* smf) {
    float* sc = smf; float* sh = smf + 64;
    int tid = threadIdx.x;
    if (tid < 64) {
        float m = sums[tid] * (1.0f / NN);
        float var = sums[64 + tid] * (1.0f / NN) - m * m;
        if (var < 0.f) var = 0.f;
        float s = g[tid] * rsqrtf(var + BN_EPS);
        sc[tid] = s;
        sh[tid] = be[tid] - m * s;
    }
    __syncthreads();
    for (int blk = blockIdx.x; blk < 3125; blk += GRID) {
        int i = blk * 256 + tid;  // over NN*16 float4s
        if (i < NN * 16) {
            int row = i >> 4, f = (i & 15) * 4;
            f32x4 v = *(const f32x4*)(T + (size_t)row * 64 + f);
            s16x4 ub;
            #pragma unroll
            for (int j = 0; j < 4; j++) {
                float w = v[j] * sc[f + j] + sh[f + j];
                ub[j] = f2bs(w > 0.f ? w : 0.f);
            }
            *(s16x4*)(Hb + (size_t)row * 64 + f) = ub;
        }
    }
}

// ---- final GEMM: [h1 | relu(bn(T2))] (Nx128) @ Wtf + bias -> out --------------
__device__ __forceinline__ void fin_phase(int blk, const short* __restrict__ Hp,
        const float* __restrict__ T2, const float* __restrict__ stats,
        const float* __restrict__ g, const float* __restrict__ be,
        const short* __restrict__ Wtf, const float* __restrict__ bias,
        float* __restrict__ O, float* smf) {
    float* sc = smf; float* sh = smf + 64;
    int tid = threadIdx.x;
    if (tid < 64) {
        float mm = stats[tid] * (1.0f / NN);
        float var = stats[64 + tid] * (1.0f / NN) - mm * mm;
        if (var < 0.f) var = 0.f;
        float s = g[tid] * rsqrtf(var + BN_EPS);
        sc[tid] = s;
        sh[tid] = be[tid] - mm * s;
    }
    __syncthreads();
    int wv = tid >> 6, L = tid & 63;
    int m = L & 15, quad = L >> 4;
    int wrow = blk * 64 + wv * 16;
    int arow = wrow + m;
    if (arow >= NN) arow = NN - 1;
    s16x8 a0 = *(const s16x8*)(Hp + (size_t)arow * 64 + quad * 8);
    s16x8 a1 = *(const s16x8*)(Hp + (size_t)arow * 64 + 32 + quad * 8);
    f32x4 t0 = *(const f32x4*)(T2 + (size_t)arow * 64 + quad * 8);
    f32x4 t1 = *(const f32x4*)(T2 + (size_t)arow * 64 + quad * 8 + 4);
    f32x4 t2 = *(const f32x4*)(T2 + (size_t)arow * 64 + 32 + quad * 8);
    f32x4 t3 = *(const f32x4*)(T2 + (size_t)arow * 64 + 32 + quad * 8 + 4);
    s16x8 a2, a3;
    #pragma unroll
    for (int j = 0; j < 4; j++) {
        int k0 = quad * 8 + j, k1 = quad * 8 + 4 + j;
        float u0 = t0[j] * sc[k0] + sh[k0]; a2[j]     = f2bs(u0 > 0.f ? u0 : 0.f);
        float u1 = t1[j] * sc[k1] + sh[k1]; a2[4 + j] = f2bs(u1 > 0.f ? u1 : 0.f);
        float u2 = t2[j] * sc[32 + k0] + sh[32 + k0]; a3[j]     = f2bs(u2 > 0.f ? u2 : 0.f);
        float u3 = t3[j] * sc[32 + k1] + sh[32 + k1]; a3[4 + j] = f2bs(u3 > 0.f ? u3 : 0.f);
    }
    f32x4 acc[4];
    #pragma unroll
    for (int nt = 0; nt < 4; nt++) {
        int n = nt * 16 + m;
        s16x8 b0 = *(const s16x8*)(Wtf + n * 128 + quad * 8);
        s16x8 b1 = *(const s16x8*)(Wtf + n * 128 + 32 + quad * 8);
        s16x8 b2 = *(const s16x8*)(Wtf + n * 128 + 64 + quad * 8);
        s16x8 b3 = *(const s16x8*)(Wtf + n * 128 + 96 + quad * 8);
        acc[nt] = (f32x4){0.f, 0.f, 0.f, 0.f};
        acc[nt] = __builtin_amdgcn_mfma_f32_16x16x32_bf16(a0, b0, acc[nt], 0, 0, 0);
        acc[nt] = __builtin_amdgcn_mfma_f32_16x16x32_bf16(a1, b1, acc[nt], 0, 0, 0);
        acc[nt] = __builtin_amdgcn_mfma_f32_16x16x32_bf16(a2, b2, acc[nt], 0, 0, 0);
        acc[nt] = __builtin_amdgcn_mfma_f32_16x16x32_bf16(a3, b3, acc[nt], 0, 0, 0);
    }
    #pragma unroll
    for (int nt = 0; nt < 4; nt++) {
        int col = nt * 16 + m;
        float bv = bias[col];
        #pragma unroll
        for (int r = 0; r < 4; r++) {
            int orow = wrow + quad * 4 + r;
            if (orow < NN) O[(size_t)orow * 64 + col] = acc[nt][r] + bv;
        }
    }
}

// ================= single persistent kernel: whole pipeline ====================
__global__ __launch_bounds__(256, 4) void fused_all(Params P) {
    __shared__ int smem[5376];          // 21504 B arena, max user = bscatter
    float* smf = (float*)smem;
    int t = threadIdx.x;

    // ---- stage 0: prep (hist chunks / x->bf16 / W^T->bf16), grid-stride ------
    for (int b = blockIdx.x; b < NPREP; b += GRID) {
        if (b < NCH) {
            int* c = smem;
            c[t] = 0;
            __syncthreads();
            int base = b * CHUNK;
            int n = NE - base; if (n > CHUNK) n = CHUNK;
            for (int i = t; i < n; i += 256) atomicAdd(&c[P.dst[base + i] >> 8], 1);
            __syncthreads();
            P.part[b * 256 + t] = c[t];
            __syncthreads();
        } else if (b < 196 + 3125) {
            int i = (b - 196) * 256 + t;  // over NN*16 float4s
            if (i < NN * 16) {
                f32x4 v = *(const f32x4*)(P.x + (size_t)i * 4);
                s16x4 ov;
                #pragma unroll
                for (int j = 0; j < 4; j++) ov[j] = f2bs(v[j]);
                *(s16x4*)(P.Xb + (size_t)i * 4) = ov;
            }
        } else {
            int wb = b - 3321;
            if (wb < 4) {
                const float* W = wb == 0 ? P.w0a : wb == 1 ? P.w0b : wb == 2 ? P.w1a : P.w1b;
                short* Wt = wb == 0 ? P.Wt0a : wb == 1 ? P.Wt0b : wb == 2 ? P.Wt1a : P.Wt1b;
                for (int e = t; e < 4096; e += 256) {
                    int k = e >> 6, n = e & 63;
                    Wt[n * 64 + k] = f2bs(W[e]);
                }
            } else {
                for (int e = t; e < 8192; e += 256) {
                    int k = e >> 6, n = e & 63;
                    P.Wtf[n * 128 + k] = f2bs(P.lw[e]);
                }
            }
        }
    }
    gbar(P.bar, 0);

    // ---- stage 1: bucket scan (block 0 only) + zero sums ---------------------
    if (blockIdx.x == 0) {
        int* s = smem;
        int v = 0;
        for (int c = 0; c < NCH; c++) v += P.part[c * 256 + t];
        s[t] = v;
        __syncthreads();
        for (int d = 1; d < 256; d <<= 1) {
            int u = (t >= d) ? s[t - d] : 0;
            __syncthreads();
            s[t] += u;
            __syncthreads();
        }
        int ex = s[t] - v;
        P.bbase[t] = ex;
        P.bres[t] = ex;
        if (t == 0) { P.bbase[256] = NE; P.off[NN] = NE; }
        P.sums[t] = 0.f; P.sums[256 + t] = 0.f;
    }
    gbar(P.bar, 1);

    // ---- stage 2: bucket scatter (first 196 blocks) --------------------------
    if (blockIdx.x < NCH) {
        int* cnt = smem;        int* loff = smem + 256;
        int* lcur = smem + 512; int* gst = smem + 768;
        int* sc = smem + 1024;  int* packed = smem + 1280;
        cnt[t] = 0;
        __syncthreads();
        int base = blockIdx.x * CHUNK;
        int n = NE - base; if (n > CHUNK) n = CHUNK;
        for (int i = t; i < n; i += 256) atomicAdd(&cnt[P.dst[base + i] >> 8], 1);
        __syncthreads();
        sc[t] = cnt[t];
        __syncthreads();
        for (int d = 1; d < 256; d <<= 1) {
            int u = (t >= d) ? sc[t - d] : 0;
            __syncthreads();
            sc[t] += u;
            __syncthreads();
        }
        loff[t] = sc[t] - cnt[t];
        lcur[t] = loff[t];
        __syncthreads();
        for (int i = t; i < n; i += 256) {
            int d = P.dst[base + i];
            int bb = d >> 8;
            int pp = atomicAdd(&lcur[bb], 1);
            packed[pp] = P.src[base + i] | ((d & 255) << 16) | (bb << 24);
        }
        __syncthreads();
        if (cnt[t]) gst[t] = atomicAdd(&P.bres[t], cnt[t]);
        __syncthreads();
        for (int i = t; i < n; i += 256) {
            int v = packed[i];
            int bb = (v >> 24) & 255;
            P.ebuf[gst[bb] + i - loff[bb]] = v & 0xFFFFFF;
        }
    }
    gbar(P.bar, 2);

    // ---- stage 3: per-bucket CSR (first 196 blocks) --------------------------
    if (blockIdx.x < NBK) {
        int* cnt = smem;        int* loff = smem + 256;
        int* lcur = smem + 512; int* sc = smem + 768;
        int b = blockIdx.x;
        int s0 = P.bbase[b], s1 = P.bbase[b + 1];
        int n = s1 - s0;
        cnt[t] = 0;
        __syncthreads();
        for (int i = t; i < n; i += 256) atomicAdd(&cnt[(P.ebuf[s0 + i] >> 16) & 255], 1);
        __syncthreads();
        sc[t] = cnt[t];
        __syncthreads();
        for (int d = 1; d < 256; d <<= 1) {
            int u = (t >= d) ? sc[t - d] : 0;
            __syncthreads();
            sc[t] += u;
            __syncthreads();
        }
        loff[t] = sc[t] - cnt[t];
        lcur[t] = loff[t];
        int node = b * 256 + t;
        if (node < NN) P.off[node] = s0 + loff[t];
        __syncthreads();
        for (int i = t; i < n; i += 256) {
            int v = P.ebuf[s0 + i];
            int pp = atomicAdd(&lcur[(v >> 16) & 255], 1);
            P.adj[s0 + pp] = v & 0xFFFF;
        }
    }
    gbar(P.bar, 3);

    // ---- layer 0 -------------------------------------------------------------
    for (int blk = blockIdx.x; blk < NGRP; blk += GRID)
        ggemm_phase(blk, P.Xb, P.off, P.adj, P.Wt0a, P.b0a, P.T, P.sums + 0, smf);
    gbar(P.bar, 4);
    for (int blk = blockIdx.x; blk < NGRP; blk += GRID)
        gemmbn_phase(blk, P.T, P.sums + 0, P.g0a, P.be0a, P.Wt0b, P.b0b, P.T2, P.sums + 128, smf);
    gbar(P.bar, 5);
    bn_phase(P.T2, P.sums + 128, P.g0b, P.be0b, P.HCb, smf);   // h1 bf16
    gbar(P.bar, 6);

    // ---- layer 1 -------------------------------------------------------------
    for (int blk = blockIdx.x; blk < NGRP; blk += GRID)
        ggemm_phase(blk, P.HCb, P.off, P.adj, P.Wt1a, P.b1a, P.T, P.sums + 256, smf);
    gbar(P.bar, 7);
    for (int blk = blockIdx.x; blk < NGRP; blk += GRID)
        gemmbn_phase(blk, P.T, P.sums + 256, P.g1a, P.be1a, P.Wt1b, P.b1b, P.T2, P.sums + 384, smf);
    gbar(P.bar, 8);

    // ---- JK cat + final linear ----------------------------------------------
    for (int blk = blockIdx.x; blk < NGRP; blk += GRID)
        fin_phase(blk, P.HCb, P.T2, P.sums + 384, P.g1b, P.be1b, P.Wtf, P.lb, P.out, smf);
}

// ---------------- launch ----------------
extern "C" void kernel_launch(void* const* d_in, const int* in_sizes, int n_in,
                              void* d_out, int out_size, void* d_ws, size_t ws_size,
                              hipStream_t stream) {
    const float* x   = (const float*)d_in[0];
    const int*   ei  = (const int*)d_in[1];
    (void)in_sizes; (void)n_in; (void)out_size; (void)ws_size;

    char* wsb = (char*)d_ws;
    size_t o = 0;
    auto alloc = [&](size_t bytes) -> char* {
        char* p = wsb + o;
        o += (bytes + 255) & ~(size_t)255;
        return p;
    };
    Params P;
    P.part = (int*)alloc(NCH * 256 * 4);
    P.sums = (float*)alloc(512 * 4);
    P.bbase = (int*)alloc(257 * 4);
    P.bres = (int*)alloc(256 * 4);
    P.off = (int*)alloc((NN + 1) * 4);
    P.adj = (int*)alloc(NE * 4);
    P.ebuf = (int*)alloc(NE * 4);
    P.Xb  = (short*)alloc((size_t)NN * 64 * 2);
    P.HCb = (short*)alloc((size_t)NN * 64 * 2);
    P.T  = (float*)alloc((size_t)NN * 64 * 4);
    P.T2 = (float*)alloc((size_t)NN * 64 * 4);
    P.Wt0a = (short*)alloc(4096 * 2);
    P.Wt0b = (short*)alloc(4096 * 2);
    P.Wt1a = (short*)alloc(4096 * 2);
    P.Wt1b = (short*)alloc(4096 * 2);
    P.Wtf  = (short*)alloc(8192 * 2);
    P.bar  = (unsigned*)alloc(16 * 4);

    P.src = ei;
    P.dst = ei + NE;
    P.x   = x;
    P.w0a = (const float*)d_in[2];  P.b0a = (const float*)d_in[3];
    P.g0a = (const float*)d_in[4];  P.be0a = (const float*)d_in[5];
    P.w0b = (const float*)d_in[6];  P.b0b = (const float*)d_in[7];
    P.g0b = (const float*)d_in[8];  P.be0b = (const float*)d_in[9];
    P.w1a = (const float*)d_in[10]; P.b1a = (const float*)d_in[11];
    P.g1a = (const float*)d_in[12]; P.be1a = (const float*)d_in[13];
    P.w1b = (const float*)d_in[14]; P.b1b = (const float*)d_in[15];
    P.g1b = (const float*)d_in[16]; P.be1b = (const float*)d_in[17];
    P.lw  = (const float*)d_in[18]; P.lb  = (const float*)d_in[19];
    P.out = (float*)d_out;

    hipMemsetAsync(P.bar, 0, 16 * sizeof(unsigned), stream);
    fused_all<<<GRID, 256, 0, stream>>>(P);
}

// Round 6
// 325.299 us; speedup vs baseline: 3.1193x; 3.1193x over previous
//
#include <hip/hip_runtime.h>
#include <hip/hip_bf16.h>

#define NN 50000
#define NE 800000
#define BN_EPS 1e-5f
#define CHUNK 4096
#define NCH 196    // ceil(NE / CHUNK) = 196 (196*4096 = 802816)
#define NBK 196    // ceil(NN / 256) dst-buckets
#define NSLOT 50176 // NBK*256 perm slots
#define GGRID 784   // NSLOT/64 blocks for ggemm (slot space)

typedef __attribute__((ext_vector_type(4))) float f32x4;
typedef __attribute__((ext_vector_type(8))) short s16x8;   // 8 bf16 = MFMA A/B frag
typedef __attribute__((ext_vector_type(4))) short s16x4;

__device__ __forceinline__ float bs2f(short v) {
    unsigned u = ((unsigned)(unsigned short)v) << 16;
    return __builtin_bit_cast(float, u);
}
__device__ __forceinline__ short f2bs(float v) {
    __hip_bfloat16 b = __float2bfloat16(v);
    return __builtin_bit_cast(short, b);
}

// ---- prep: [0,196) bhist chunks -> part; [196,3321) cvt x->Xb; [3321,3326) W^T->bf16
__global__ void prep_k(const int* __restrict__ dst, int* __restrict__ part,
                       const float* __restrict__ x, __hip_bfloat16* __restrict__ Xb,
                       const float* __restrict__ w0a, const float* __restrict__ w0b,
                       const float* __restrict__ w1a, const float* __restrict__ w1b,
                       const float* __restrict__ lw,
                       short* __restrict__ Wt0a, short* __restrict__ Wt0b,
                       short* __restrict__ Wt1a, short* __restrict__ Wt1b,
                       short* __restrict__ Wtf) {
    int b = blockIdx.x, t = threadIdx.x;
    if (b < NCH) {
        __shared__ int c[256];
        c[t] = 0;
        __syncthreads();
        int base = b * CHUNK;
        int n = NE - base; if (n > CHUNK) n = CHUNK;
        for (int i = t; i < n; i += 256) atomicAdd(&c[dst[base + i] >> 8], 1);
        __syncthreads();
        part[b * 256 + t] = c[t];
    } else if (b < 196 + 3125) {
        int i = (b - 196) * 256 + t;  // over NN*16 = 800000 float4s
        if (i < NN * 16) {
            f32x4 v = *(const f32x4*)(x + (size_t)i * 4);
            s16x4 ov;
            #pragma unroll
            for (int j = 0; j < 4; j++) ov[j] = f2bs(v[j]);
            *(s16x4*)((short*)Xb + (size_t)i * 4) = ov;
        }
    } else {
        int wb = b - 3321;
        if (wb < 4) {
            const float* W = wb == 0 ? w0a : wb == 1 ? w0b : wb == 2 ? w1a : w1b;
            short* Wt = wb == 0 ? Wt0a : wb == 1 ? Wt0b : wb == 2 ? Wt1a : Wt1b;
            for (int e = t; e < 4096; e += 256) {
                int k = e >> 6, n = e & 63;
                Wt[n * 64 + k] = f2bs(W[e]);
            }
        } else {
            for (int e = t; e < 8192; e += 256) {
                int k = e >> 6, n = e & 63;
                Wtf[n * 128 + k] = f2bs(lw[e]);
            }
        }
    }
}

// ---- scan bucket totals (sum part over chunks) -> bbase/bres; zero sums -------
__global__ void bscan_k(const int* __restrict__ part, int* __restrict__ bbase,
                        int* __restrict__ bres, int* __restrict__ off,
                        float* __restrict__ sums) {
    __shared__ int s[256];
    int t = threadIdx.x;
    int v = 0;
    for (int c = 0; c < NCH; c++) v += part[c * 256 + t];
    s[t] = v;
    __syncthreads();
    for (int d = 1; d < 256; d <<= 1) {
        int u = (t >= d) ? s[t - d] : 0;
        __syncthreads();
        s[t] += u;
        __syncthreads();
    }
    int ex = s[t] - v;
    bbase[t] = ex;
    bres[t] = ex;
    if (t == 0) { bbase[256] = NE; off[NN] = NE; }
    sums[t] = 0.f; sums[256 + t] = 0.f;  // 512 floats total
}

// ---- bucket scatter: chunk -> bucket-ordered ebuf (coalesced writes) ----------
// packed int: src (16b) | dst&255 (8b) | bucket (8b)
__global__ void bscatter_k(const int* __restrict__ src, const int* __restrict__ dst,
                           int* __restrict__ bres, int* __restrict__ ebuf) {
    __shared__ int cnt[256], loff[256], lcur[256], gst[256], sc[256];
    __shared__ int packed[CHUNK];
    int t = threadIdx.x;
    cnt[t] = 0;
    __syncthreads();
    int base = blockIdx.x * CHUNK;
    int n = NE - base; if (n > CHUNK) n = CHUNK;
    for (int i = t; i < n; i += 256) atomicAdd(&cnt[dst[base + i] >> 8], 1);
    __syncthreads();
    sc[t] = cnt[t];
    __syncthreads();
    for (int d = 1; d < 256; d <<= 1) {
        int u = (t >= d) ? sc[t - d] : 0;
        __syncthreads();
        sc[t] += u;
        __syncthreads();
    }
    loff[t] = sc[t] - cnt[t];
    lcur[t] = loff[t];
    __syncthreads();
    for (int i = t; i < n; i += 256) {
        int d = dst[base + i];
        int b = d >> 8;
        int p = atomicAdd(&lcur[b], 1);
        packed[p] = src[base + i] | ((d & 255) << 16) | (b << 24);
    }
    __syncthreads();
    if (cnt[t]) gst[t] = atomicAdd(&bres[t], cnt[t]);
    __syncthreads();
    for (int i = t; i < n; i += 256) {
        int v = packed[i];
        int b = (v >> 24) & 255;
        ebuf[gst[b] + i - loff[b]] = v & 0xFFFFFF;
    }
}

// ---- per-bucket CSR: off[] + adj[] + degree-sorted perm -----------------------
// After the CSR scatter, cnt[t] == in-degree of node b*256+t. A free within-
// bucket counting sort (64 bins, DESCENDING degree) produces perm so that each
// 16-node ggemm group has near-uniform degree (kills exec-mask divergence).
__global__ void csr_k(const int* __restrict__ bbase, const int* __restrict__ ebuf,
                      int* __restrict__ off, int* __restrict__ adj,
                      int* __restrict__ perm) {
    __shared__ int cnt[256], loff[256], lcur[256], sc[256];
    int b = blockIdx.x, t = threadIdx.x;
    perm[b * 256 + t] = -1;                 // holes (nonexistent nodes) stay -1
    int s0 = bbase[b], s1 = bbase[b + 1];
    int n = s1 - s0;
    cnt[t] = 0;
    __syncthreads();
    for (int i = t; i < n; i += 256) atomicAdd(&cnt[(ebuf[s0 + i] >> 16) & 255], 1);
    __syncthreads();
    sc[t] = cnt[t];
    __syncthreads();
    for (int d = 1; d < 256; d <<= 1) {
        int u = (t >= d) ? sc[t - d] : 0;
        __syncthreads();
        sc[t] += u;
        __syncthreads();
    }
    loff[t] = sc[t] - cnt[t];
    lcur[t] = loff[t];
    int node = b * 256 + t;
    if (node < NN) off[node] = s0 + loff[t];
    __syncthreads();
    for (int i = t; i < n; i += 256) {
        int v = ebuf[s0 + i];
        int p = atomicAdd(&lcur[(v >> 16) & 255], 1);
        adj[s0 + p] = v & 0xFFFF;
    }
    // ---- within-bucket degree sort (descending) -> perm ----------------------
    __syncthreads();
    int key = -1;
    if (node < NN) {
        int deg = cnt[t];
        if (deg > 63) deg = 63;
        key = 63 - deg;                     // ascending key == descending degree
    }
    if (t < 64) loff[t] = 0;                // reuse loff as 64-bin hist
    __syncthreads();
    if (key >= 0) atomicAdd(&loff[key], 1);
    __syncthreads();
    if (t < 64) sc[t] = loff[t];
    __syncthreads();
    for (int d = 1; d < 64; d <<= 1) {
        int u = (t >= d && t < 64) ? sc[t - d] : 0;
        __syncthreads();
        if (t < 64) sc[t] += u;
        __syncthreads();
    }
    if (t < 64) lcur[t] = sc[t] - loff[t];  // exclusive base per key
    __syncthreads();
    if (key >= 0) {
        int r = atomicAdd(&lcur[key], 1);
        perm[b * 256 + r] = node;
    }
}

// ---- FUSED gather + MFMA GEMM + bias + BN stats -> T fp32 ---------------------
// wave = 16 SLOTS x 64 cols; slot -> node via degree-sorted perm, so all 16
// lanes have near-equal edge counts (divergence-free loop trip count).
// lane L: slot m=(L&15), feature slices [quad*8,+8) and [32+quad*8,+8).
__global__ void ggemm_k(const __hip_bfloat16* __restrict__ X,
                        const int* __restrict__ off, const int* __restrict__ adj,
                        const int* __restrict__ perm,
                        const short* __restrict__ Wt,    // 64x64 bf16, [n][k]
                        const float* __restrict__ bias,
                        float* __restrict__ T,
                        float* __restrict__ sums) {
    __shared__ float lsum[64], lssq[64];
    int t = threadIdx.x;
    if (t < 64) { lsum[t] = 0.f; lssq[t] = 0.f; }
    __syncthreads();
    int wv = t >> 6, L = t & 63;
    int m = L & 15, quad = L >> 4;
    int wrow = blockIdx.x * 64 + wv * 16;
    int pn = perm[wrow + m];
    int node = pn < 0 ? NN - 1 : pn;        // dup row for holes; guarded below
    const short* Xp = (const short*)X;

    // self row slice (GIN: (1+eps)*x_i with eps=0)
    const short* rp = Xp + (size_t)node * 64 + quad * 8;
    s16x8 sl = *(const s16x8*)rp;
    s16x8 shh = *(const s16x8*)(rp + 32);
    float aL[8], aH[8];
    #pragma unroll
    for (int j = 0; j < 8; j++) { aL[j] = bs2f(sl[j]); aH[j] = bs2f(shh[j]); }

    int s = off[node], e = off[node + 1];
    if (pn < 0) e = s;                      // holes gather nothing
    int p = s;
    // 8-edge pipeline: 16 independent 16B loads in flight per lane
    for (; p + 8 <= e; p += 8) {
        int jx[8];
        #pragma unroll
        for (int q = 0; q < 8; q++) jx[q] = adj[p + q];
        s16x8 v[8], w[8];
        #pragma unroll
        for (int q = 0; q < 8; q++) {
            const short* r = Xp + (size_t)jx[q] * 64 + quad * 8;
            v[q] = *(const s16x8*)r;
            w[q] = *(const s16x8*)(r + 32);
        }
        #pragma unroll
        for (int j = 0; j < 8; j++) {
            float sv = ((bs2f(v[0][j]) + bs2f(v[1][j])) + (bs2f(v[2][j]) + bs2f(v[3][j])))
                     + ((bs2f(v[4][j]) + bs2f(v[5][j])) + (bs2f(v[6][j]) + bs2f(v[7][j])));
            float sw = ((bs2f(w[0][j]) + bs2f(w[1][j])) + (bs2f(w[2][j]) + bs2f(w[3][j])))
                     + ((bs2f(w[4][j]) + bs2f(w[5][j])) + (bs2f(w[6][j]) + bs2f(w[7][j])));
            aL[j] += sv;
            aH[j] += sw;
        }
    }
    if (p + 4 <= e) {
        int j0 = adj[p], j1 = adj[p + 1], j2 = adj[p + 2], j3 = adj[p + 3];
        const short* r0 = Xp + (size_t)j0 * 64 + quad * 8;
        const short* r1 = Xp + (size_t)j1 * 64 + quad * 8;
        const short* r2 = Xp + (size_t)j2 * 64 + quad * 8;
        const short* r3 = Xp + (size_t)j3 * 64 + quad * 8;
        s16x8 v0 = *(const s16x8*)r0, w0 = *(const s16x8*)(r0 + 32);
        s16x8 v1 = *(const s16x8*)r1, w1 = *(const s16x8*)(r1 + 32);
        s16x8 v2 = *(const s16x8*)r2, w2 = *(const s16x8*)(r2 + 32);
        s16x8 v3 = *(const s16x8*)r3, w3 = *(const s16x8*)(r3 + 32);
        #pragma unroll
        for (int j = 0; j < 8; j++) {
            aL[j] += (bs2f(v0[j]) + bs2f(v1[j])) + (bs2f(v2[j]) + bs2f(v3[j]));
            aH[j] += (bs2f(w0[j]) + bs2f(w1[j])) + (bs2f(w2[j]) + bs2f(w3[j]));
        }
        p += 4;
    }
    for (; p < e; p++) {
        int j0 = adj[p];
        const short* r0 = Xp + (size_t)j0 * 64 + quad * 8;
        s16x8 v0 = *(const s16x8*)r0, w0 = *(const s16x8*)(r0 + 32);
        #pragma unroll
        for (int j = 0; j < 8; j++) { aL[j] += bs2f(v0[j]); aH[j] += bs2f(w0[j]); }
    }

    s16x8 a0, a1;
    #pragma unroll
    for (int j = 0; j < 8; j++) { a0[j] = f2bs(aL[j]); a1[j] = f2bs(aH[j]); }

    f32x4 acc[4];
    #pragma unroll
    for (int nt = 0; nt < 4; nt++) {
        int n = nt * 16 + m;
        s16x8 b0 = *(const s16x8*)(Wt + n * 64 + quad * 8);
        s16x8 b1 = *(const s16x8*)(Wt + n * 64 + 32 + quad * 8);
        acc[nt] = (f32x4){0.f, 0.f, 0.f, 0.f};
        acc[nt] = __builtin_amdgcn_mfma_f32_16x16x32_bf16(a0, b0, acc[nt], 0, 0, 0);
        acc[nt] = __builtin_amdgcn_mfma_f32_16x16x32_bf16(a1, b1, acc[nt], 0, 0, 0);
    }
    int onode[4];
    #pragma unroll
    for (int r = 0; r < 4; r++) onode[r] = perm[wrow + quad * 4 + r];
    #pragma unroll
    for (int nt = 0; nt < 4; nt++) {
        int col = nt * 16 + m;
        float bv = bias[col];
        float ps = 0.f, pq = 0.f;
        #pragma unroll
        for (int r = 0; r < 4; r++) {
            if (onode[r] >= 0) {
                float v = acc[nt][r] + bv;
                T[(size_t)onode[r] * 64 + col] = v;
                ps += v;
                pq += v * v;
            }
        }
        atomicAdd(&lsum[col], ps);
        atomicAdd(&lssq[col], pq);
    }
    __syncthreads();
    if (t < 64) {
        atomicAdd(&sums[t], lsum[t]);
        atomicAdd(&sums[64 + t], lssq[t]);
    }
}

// ---- GEMM with A = relu(bn(T)) built on the fly -> Tout fp32 + stats ----------
__global__ void gemm_bn_k(const float* __restrict__ Tin,
                          const float* __restrict__ stats,
                          const float* __restrict__ g, const float* __restrict__ be,
                          const short* __restrict__ Wt,    // 64x64 bf16 [n][k]
                          const float* __restrict__ bias,
                          float* __restrict__ T,
                          float* __restrict__ sums) {
    __shared__ float sc[64], sh[64], lsum[64], lssq[64];
    int tid = threadIdx.x;
    if (tid < 64) {
        float mm = stats[tid] * (1.0f / NN);
        float var = stats[64 + tid] * (1.0f / NN) - mm * mm;
        if (var < 0.f) var = 0.f;
        float s = g[tid] * rsqrtf(var + BN_EPS);
        sc[tid] = s;
        sh[tid] = be[tid] - mm * s;
        lsum[tid] = 0.f; lssq[tid] = 0.f;
    }
    __syncthreads();
    int wv = tid >> 6, L = tid & 63;
    int m = L & 15, quad = L >> 4;
    int wrow = blockIdx.x * 64 + wv * 16;
    int arow = wrow + m;
    if (arow >= NN) arow = NN - 1;
    f32x4 t0 = *(const f32x4*)(Tin + (size_t)arow * 64 + quad * 8);
    f32x4 t1 = *(const f32x4*)(Tin + (size_t)arow * 64 + quad * 8 + 4);
    f32x4 t2 = *(const f32x4*)(Tin + (size_t)arow * 64 + 32 + quad * 8);
    f32x4 t3 = *(const f32x4*)(Tin + (size_t)arow * 64 + 32 + quad * 8 + 4);
    s16x8 a0, a1;
    #pragma unroll
    for (int j = 0; j < 4; j++) {
        int k0 = quad * 8 + j, k1 = quad * 8 + 4 + j;
        float u0 = t0[j] * sc[k0] + sh[k0]; a0[j]     = f2bs(u0 > 0.f ? u0 : 0.f);
        float u1 = t1[j] * sc[k1] + sh[k1]; a0[4 + j] = f2bs(u1 > 0.f ? u1 : 0.f);
        float u2 = t2[j] * sc[32 + k0] + sh[32 + k0]; a1[j]     = f2bs(u2 > 0.f ? u2 : 0.f);
        float u3 = t3[j] * sc[32 + k1] + sh[32 + k1]; a1[4 + j] = f2bs(u3 > 0.f ? u3 : 0.f);
    }
    f32x4 acc[4];
    #pragma unroll
    for (int nt = 0; nt < 4; nt++) {
        int n = nt * 16 + m;
        s16x8 b0 = *(const s16x8*)(Wt + n * 64 + quad * 8);
        s16x8 b1 = *(const s16x8*)(Wt + n * 64 + 32 + quad * 8);
        acc[nt] = (f32x4){0.f, 0.f, 0.f, 0.f};
        acc[nt] = __builtin_amdgcn_mfma_f32_16x16x32_bf16(a0, b0, acc[nt], 0, 0, 0);
        acc[nt] = __builtin_amdgcn_mfma_f32_16x16x32_bf16(a1, b1, acc[nt], 0, 0, 0);
    }
    #pragma unroll
    for (int nt = 0; nt < 4; nt++) {
        int col = nt * 16 + m;
        float bv = bias[col];
        float ps = 0.f, pq = 0.f;
        #pragma unroll
        for (int r = 0; r < 4; r++) {
            int orow = wrow + quad * 4 + r;
            if (orow < NN) {
                float v = acc[nt][r] + bv;
                T[(size_t)orow * 64 + col] = v;
                ps += v;
                pq += v * v;
            }
        }
        atomicAdd(&lsum[col], ps);
        atomicAdd(&lssq[col], pq);
    }
    __syncthreads();
    if (tid < 64) {
        atomicAdd(&sums[tid], lsum[tid]);
        atomicAdd(&sums[64 + tid], lssq[tid]);
    }
}

// ---- BN finalize + apply + ReLU: T2 fp32 -> HCb bf16 --------------------------
__global__ void bn_k(const float* __restrict__ T, const float* __restrict__ sums,
                     const float* __restrict__ g, const float* __restrict__ be,
                     __hip_bfloat16* __restrict__ Hb) {
    __shared__ float sc[64], sh[64];
    int tid = threadIdx.x;
    if (tid < 64) {
        float m = sums[tid] * (1.0f / NN);
        float var = sums[64 + tid] * (1.0f / NN) - m * m;
        if (var < 0.f) var = 0.f;
        float s = g[tid] * rsqrtf(var + BN_EPS);
        sc[tid] = s;
        sh[tid] = be[tid] - m * s;
    }
    __syncthreads();
    int i = blockIdx.x * 256 + tid;  // over NN*16 float4s
    if (i < NN * 16) {
        int row = i >> 4, f = (i & 15) * 4;
        f32x4 v = *(const f32x4*)(T + (size_t)row * 64 + f);
        s16x4 ub;
        #pragma unroll
        for (int j = 0; j < 4; j++) {
            float w = v[j] * sc[f + j] + sh[f + j];
            ub[j] = f2bs(w > 0.f ? w : 0.f);
        }
        *(s16x4*)((short*)Hb + (size_t)row * 64 + f) = ub;
    }
}

// ---- final MFMA GEMM: [h1(bf16) | relu(bn(T2))] (Nx128) @ Wtf -> fp32 out -----
__global__ void gemm_fin_k(const __hip_bfloat16* __restrict__ H1b,
                           const float* __restrict__ T2,
                           const float* __restrict__ stats,
                           const float* __restrict__ g, const float* __restrict__ be,
                           const short* __restrict__ Wtf,   // [n][k], k=128, bf16
                           const float* __restrict__ bias,
                           float* __restrict__ O) {
    __shared__ float sc[64], sh[64];
    int tid = threadIdx.x;
    if (tid < 64) {
        float mm = stats[tid] * (1.0f / NN);
        float var = stats[64 + tid] * (1.0f / NN) - mm * mm;
        if (var < 0.f) var = 0.f;
        float s = g[tid] * rsqrtf(var + BN_EPS);
        sc[tid] = s;
        sh[tid] = be[tid] - mm * s;
    }
    __syncthreads();
    int wv = tid >> 6, L = tid & 63;
    int m = L & 15, quad = L >> 4;
    int wrow = blockIdx.x * 64 + wv * 16;
    int arow = wrow + m;
    if (arow >= NN) arow = NN - 1;
    const short* Hp = (const short*)H1b;
    s16x8 a0 = *(const s16x8*)(Hp + (size_t)arow * 64 + quad * 8);
    s16x8 a1 = *(const s16x8*)(Hp + (size_t)arow * 64 + 32 + quad * 8);
    f32x4 t0 = *(const f32x4*)(T2 + (size_t)arow * 64 + quad * 8);
    f32x4 t1 = *(const f32x4*)(T2 + (size_t)arow * 64 + quad * 8 + 4);
    f32x4 t2 = *(const f32x4*)(T2 + (size_t)arow * 64 + 32 + quad * 8);
    f32x4 t3 = *(const f32x4*)(T2 + (size_t)arow * 64 + 32 + quad * 8 + 4);
    s16x8 a2, a3;
    #pragma unroll
    for (int j = 0; j < 4; j++) {
        int k0 = quad * 8 + j, k1 = quad * 8 + 4 + j;
        float u0 = t0[j] * sc[k0] + sh[k0]; a2[j]     = f2bs(u0 > 0.f ? u0 : 0.f);
        float u1 = t1[j] * sc[k1] + sh[k1]; a2[4 + j] = f2bs(u1 > 0.f ? u1 : 0.f);
        float u2 = t2[j] * sc[32 + k0] + sh[32 + k0]; a3[j]     = f2bs(u2 > 0.f ? u2 : 0.f);
        float u3 = t3[j] * sc[32 + k1] + sh[32 + k1]; a3[4 + j] = f2bs(u3 > 0.f ? u3 : 0.f);
    }
    f32x4 acc[4];
    #pragma unroll
    for (int nt = 0; nt < 4; nt++) {
        int n = nt * 16 + m;
        s16x8 b0 = *(const s16x8*)(Wtf + n * 128 + quad * 8);
        s16x8 b1 = *(const s16x8*)(Wtf + n * 128 + 32 + quad * 8);
        s16x8 b2 = *(const s16x8*)(Wtf + n * 128 + 64 + quad * 8);
        s16x8 b3 = *(const s16x8*)(Wtf + n * 128 + 96 + quad * 8);
        acc[nt] = (f32x4){0.f, 0.f, 0.f, 0.f};
        acc[nt] = __builtin_amdgcn_mfma_f32_16x16x32_bf16(a0, b0, acc[nt], 0, 0, 0);
        acc[nt] = __builtin_amdgcn_mfma_f32_16x16x32_bf16(a1, b1, acc[nt], 0, 0, 0);
        acc[nt] = __builtin_amdgcn_mfma_f32_16x16x32_bf16(a2, b2, acc[nt], 0, 0, 0);
        acc[nt] = __builtin_amdgcn_mfma_f32_16x16x32_bf16(a3, b3, acc[nt], 0, 0, 0);
    }
    #pragma unroll
    for (int nt = 0; nt < 4; nt++) {
        int col = nt * 16 + m;
        float bv = bias[col];
        #pragma unroll
        for (int r = 0; r < 4; r++) {
            int orow = wrow + quad * 4 + r;
            if (orow < NN) O[(size_t)orow * 64 + col] = acc[nt][r] + bv;
        }
    }
}

// ---------------- launch ----------------
extern "C" void kernel_launch(void* const* d_in, const int* in_sizes, int n_in,
                              void* d_out, int out_size, void* d_ws, size_t ws_size,
                              hipStream_t stream) {
    const float* x   = (const float*)d_in[0];
    const int*   ei  = (const int*)d_in[1];
    const float* w0a = (const float*)d_in[2];
    const float* b0a = (const float*)d_in[3];
    const float* g0a = (const float*)d_in[4];
    const float* be0a= (const float*)d_in[5];
    const float* w0b = (const float*)d_in[6];
    const float* b0b = (const float*)d_in[7];
    const float* g0b = (const float*)d_in[8];
    const float* be0b= (const float*)d_in[9];
    const float* w1a = (const float*)d_in[10];
    const float* b1a = (const float*)d_in[11];
    const float* g1a = (const float*)d_in[12];
    const float* be1a= (const float*)d_in[13];
    const float* w1b = (const float*)d_in[14];
    const float* b1b = (const float*)d_in[15];
    const float* g1b = (const float*)d_in[16];
    const float* be1b= (const float*)d_in[17];
    const float* lw  = (const float*)d_in[18];
    const float* lb  = (const float*)d_in[19];
    float* out = (float*)d_out;
    (void)in_sizes; (void)n_in; (void)out_size; (void)ws_size;

    char* wsb = (char*)d_ws;
    size_t o = 0;
    auto alloc = [&](size_t bytes) -> char* {
        char* p = wsb + o;
        o += (bytes + 255) & ~(size_t)255;
        return p;
    };
    int* part = (int*)alloc(NCH * 256 * 4);
    float* sums = (float*)alloc(512 * 4);
    int* bbase = (int*)alloc(257 * 4);
    int* bres = (int*)alloc(256 * 4);
    int* off = (int*)alloc((NN + 1) * 4);
    int* adj = (int*)alloc(NE * 4);
    int* ebuf = (int*)alloc(NE * 4);
    int* perm = (int*)alloc(NSLOT * 4);
    __hip_bfloat16* Xb  = (__hip_bfloat16*)alloc((size_t)NN * 64 * 2);
    __hip_bfloat16* HCb = (__hip_bfloat16*)alloc((size_t)NN * 64 * 2);
    float* T  = (float*)alloc((size_t)NN * 64 * 4);
    float* T2 = (float*)alloc((size_t)NN * 64 * 4);
    short* Wt0a = (short*)alloc(4096 * 2);
    short* Wt0b = (short*)alloc(4096 * 2);
    short* Wt1a = (short*)alloc(4096 * 2);
    short* Wt1b = (short*)alloc(4096 * 2);
    short* Wtf  = (short*)alloc(8192 * 2);

    const int* src = ei;
    const int* dst = ei + NE;

    prep_k<<<3326, 256, 0, stream>>>(dst, part, x, Xb, w0a, w0b, w1a, w1b, lw,
                                     Wt0a, Wt0b, Wt1a, Wt1b, Wtf);
    bscan_k<<<1, 256, 0, stream>>>(part, bbase, bres, off, sums);
    bscatter_k<<<NCH, 256, 0, stream>>>(src, dst, bres, ebuf);
    csr_k<<<NBK, 256, 0, stream>>>(bbase, ebuf, off, adj, perm);

    const int mgrid = (NN + 63) / 64;          // 782
    const int agrid = (NN * 16 + 255) / 256;   // 3125

    // ---- layer 0 ----
    ggemm_k<<<GGRID, 256, 0, stream>>>(Xb, off, adj, perm, Wt0a, b0a, T, sums + 0);
    gemm_bn_k<<<mgrid, 256, 0, stream>>>(T, sums + 0, g0a, be0a, Wt0b, b0b, T2, sums + 128);
    bn_k<<<agrid, 256, 0, stream>>>(T2, sums + 128, g0b, be0b, HCb);          // h1 bf16
    // ---- layer 1 ----
    ggemm_k<<<GGRID, 256, 0, stream>>>(HCb, off, adj, perm, Wt1a, b1a, T, sums + 256);
    gemm_bn_k<<<mgrid, 256, 0, stream>>>(T, sums + 256, g1a, be1a, Wt1b, b1b, T2, sums + 384);
    // ---- JK cat + final linear (h2 BN fused; h1 read as bf16) ----
    gemm_fin_k<<<mgrid, 256, 0, stream>>>(HCb, T2, sums + 384, g1b, be1b, Wtf, lb, out);
}

// Round 7
// 320.343 us; speedup vs baseline: 3.1676x; 1.0155x over previous
//
#include <hip/hip_runtime.h>
#include <hip/hip_bf16.h>

#define NN 50000
#define NE 800000
#define BN_EPS 1e-5f
#define CHUNK 4096
#define NCH 196    // ceil(NE / CHUNK) = 196 (196*4096 = 802816)
#define NBK 196    // ceil(NN / 256) dst-buckets

typedef __attribute__((ext_vector_type(4))) float f32x4;
typedef __attribute__((ext_vector_type(8))) short s16x8;   // 8 bf16 = MFMA A/B frag
typedef __attribute__((ext_vector_type(4))) short s16x4;

__device__ __forceinline__ float bs2f(short v) {
    unsigned u = ((unsigned)(unsigned short)v) << 16;
    return __builtin_bit_cast(float, u);
}
__device__ __forceinline__ short f2bs(float v) {
    __hip_bfloat16 b = __float2bfloat16(v);
    return __builtin_bit_cast(short, b);
}

// ---- prep: [0,196) bhist chunks -> part; [196,3321) cvt x->Xb; [3321,3326) W^T->bf16
__global__ void prep_k(const int* __restrict__ dst, int* __restrict__ part,
                       const float* __restrict__ x, __hip_bfloat16* __restrict__ Xb,
                       const float* __restrict__ w0a, const float* __restrict__ w0b,
                       const float* __restrict__ w1a, const float* __restrict__ w1b,
                       const float* __restrict__ lw,
                       short* __restrict__ Wt0a, short* __restrict__ Wt0b,
                       short* __restrict__ Wt1a, short* __restrict__ Wt1b,
                       short* __restrict__ Wtf) {
    int b = blockIdx.x, t = threadIdx.x;
    if (b < NCH) {
        __shared__ int c[256];
        c[t] = 0;
        __syncthreads();
        int base = b * CHUNK;
        int n = NE - base; if (n > CHUNK) n = CHUNK;
        for (int i = t; i < n; i += 256) atomicAdd(&c[dst[base + i] >> 8], 1);
        __syncthreads();
        part[b * 256 + t] = c[t];
    } else if (b < 196 + 3125) {
        int i = (b - 196) * 256 + t;  // over NN*16 = 800000 float4s
        if (i < NN * 16) {
            f32x4 v = *(const f32x4*)(x + (size_t)i * 4);
            s16x4 ov;
            #pragma unroll
            for (int j = 0; j < 4; j++) ov[j] = f2bs(v[j]);
            *(s16x4*)((short*)Xb + (size_t)i * 4) = ov;
        }
    } else {
        int wb = b - 3321;
        if (wb < 4) {
            const float* W = wb == 0 ? w0a : wb == 1 ? w0b : wb == 2 ? w1a : w1b;
            short* Wt = wb == 0 ? Wt0a : wb == 1 ? Wt0b : wb == 2 ? Wt1a : Wt1b;
            for (int e = t; e < 4096; e += 256) {
                int k = e >> 6, n = e & 63;
                Wt[n * 64 + k] = f2bs(W[e]);
            }
        } else {
            for (int e = t; e < 8192; e += 256) {
                int k = e >> 6, n = e & 63;
                Wtf[n * 128 + k] = f2bs(lw[e]);
            }
        }
    }
}

// ---- scan bucket totals (sum part over chunks) -> bbase/bres; zero sums -------
__global__ void bscan_k(const int* __restrict__ part, int* __restrict__ bbase,
                        int* __restrict__ bres, int* __restrict__ off,
                        float* __restrict__ sums) {
    __shared__ int s[256];
    int t = threadIdx.x;
    int v = 0;
    for (int c = 0; c < NCH; c++) v += part[c * 256 + t];
    s[t] = v;
    __syncthreads();
    for (int d = 1; d < 256; d <<= 1) {
        int u = (t >= d) ? s[t - d] : 0;
        __syncthreads();
        s[t] += u;
        __syncthreads();
    }
    int ex = s[t] - v;
    bbase[t] = ex;
    bres[t] = ex;
    if (t == 0) { bbase[256] = NE; off[NN] = NE; }
    sums[t] = 0.f; sums[256 + t] = 0.f;  // 512 floats total
}

// ---- bucket scatter: chunk -> bucket-ordered ebuf (coalesced writes) ----------
// packed int: src (16b) | dst&255 (8b) | bucket (8b)
__global__ void bscatter_k(const int* __restrict__ src, const int* __restrict__ dst,
                           int* __restrict__ bres, int* __restrict__ ebuf) {
    __shared__ int cnt[256], loff[256], lcur[256], gst[256], sc[256];
    __shared__ int packed[CHUNK];
    int t = threadIdx.x;
    cnt[t] = 0;
    __syncthreads();
    int base = blockIdx.x * CHUNK;
    int n = NE - base; if (n > CHUNK) n = CHUNK;
    for (int i = t; i < n; i += 256) atomicAdd(&cnt[dst[base + i] >> 8], 1);
    __syncthreads();
    sc[t] = cnt[t];
    __syncthreads();
    for (int d = 1; d < 256; d <<= 1) {
        int u = (t >= d) ? sc[t - d] : 0;
        __syncthreads();
        sc[t] += u;
        __syncthreads();
    }
    loff[t] = sc[t] - cnt[t];
    lcur[t] = loff[t];
    __syncthreads();
    for (int i = t; i < n; i += 256) {
        int d = dst[base + i];
        int b = d >> 8;
        int p = atomicAdd(&lcur[b], 1);
        packed[p] = src[base + i] | ((d & 255) << 16) | (b << 24);
    }
    __syncthreads();
    if (cnt[t]) gst[t] = atomicAdd(&bres[t], cnt[t]);
    __syncthreads();
    for (int i = t; i < n; i += 256) {
        int v = packed[i];
        int b = (v >> 24) & 255;
        ebuf[gst[b] + i - loff[b]] = v & 0xFFFFFF;
    }
}

// ---- per-bucket CSR: off[] + adj[] --------------------------------------------
__global__ void csr_k(const int* __restrict__ bbase, const int* __restrict__ ebuf,
                      int* __restrict__ off, int* __restrict__ adj) {
    __shared__ int cnt[256], loff[256], lcur[256], sc[256];
    int b = blockIdx.x, t = threadIdx.x;
    int s0 = bbase[b], s1 = bbase[b + 1];
    int n = s1 - s0;
    cnt[t] = 0;
    __syncthreads();
    for (int i = t; i < n; i += 256) atomicAdd(&cnt[(ebuf[s0 + i] >> 16) & 255], 1);
    __syncthreads();
    sc[t] = cnt[t];
    __syncthreads();
    for (int d = 1; d < 256; d <<= 1) {
        int u = (t >= d) ? sc[t - d] : 0;
        __syncthreads();
        sc[t] += u;
        __syncthreads();
    }
    loff[t] = sc[t] - cnt[t];
    lcur[t] = loff[t];
    int node = b * 256 + t;
    if (node < NN) off[node] = s0 + loff[t];
    __syncthreads();
    for (int i = t; i < n; i += 256) {
        int v = ebuf[s0 + i];
        int p = atomicAdd(&lcur[(v >> 16) & 255], 1);
        adj[s0 + p] = v & 0xFFFF;
    }
}

// ---- FUSED gather + MFMA GEMM + bias + BN stats -> T fp32 ---------------------
// wave = 16 nodes x 64 cols; lane L serves node m=(L&15), feature slices
// [quad*8,+8) and [32+quad*8,+8). T stores are NON-TEMPORAL: T is written once
// and read once by the next kernel; keeping it out of L2 preserves X/HCb
// residency for the random row gather (X=6.4MB vs 4MB L2/XCD).
__global__ void ggemm_k(const __hip_bfloat16* __restrict__ X,
                        const int* __restrict__ off, const int* __restrict__ adj,
                        const short* __restrict__ Wt,    // 64x64 bf16, [n][k]
                        const float* __restrict__ bias,
                        float* __restrict__ T,
                        float* __restrict__ sums) {
    __shared__ float lsum[64], lssq[64];
    int t = threadIdx.x;
    if (t < 64) { lsum[t] = 0.f; lssq[t] = 0.f; }
    __syncthreads();
    int wv = t >> 6, L = t & 63;
    int m = L & 15, quad = L >> 4;
    int wrow = blockIdx.x * 64 + wv * 16;
    int node = wrow + m;
    if (node >= NN) node = NN - 1;  // dup row; stores/stats guarded below
    const short* Xp = (const short*)X;

    // self row slice (GIN: (1+eps)*x_i with eps=0)
    const short* rp = Xp + (size_t)node * 64 + quad * 8;
    s16x8 sl = *(const s16x8*)rp;
    s16x8 shh = *(const s16x8*)(rp + 32);
    float aL[8], aH[8];
    #pragma unroll
    for (int j = 0; j < 8; j++) { aL[j] = bs2f(sl[j]); aH[j] = bs2f(shh[j]); }

    int s = off[node], e = off[node + 1];
    int p = s;
    // 8-edge pipeline: 16 independent 16B loads in flight per lane
    for (; p + 8 <= e; p += 8) {
        int jx[8];
        #pragma unroll
        for (int q = 0; q < 8; q++) jx[q] = adj[p + q];
        s16x8 v[8], w[8];
        #pragma unroll
        for (int q = 0; q < 8; q++) {
            const short* r = Xp + (size_t)jx[q] * 64 + quad * 8;
            v[q] = *(const s16x8*)r;
            w[q] = *(const s16x8*)(r + 32);
        }
        #pragma unroll
        for (int j = 0; j < 8; j++) {
            float sv = ((bs2f(v[0][j]) + bs2f(v[1][j])) + (bs2f(v[2][j]) + bs2f(v[3][j])))
                     + ((bs2f(v[4][j]) + bs2f(v[5][j])) + (bs2f(v[6][j]) + bs2f(v[7][j])));
            float sw = ((bs2f(w[0][j]) + bs2f(w[1][j])) + (bs2f(w[2][j]) + bs2f(w[3][j])))
                     + ((bs2f(w[4][j]) + bs2f(w[5][j])) + (bs2f(w[6][j]) + bs2f(w[7][j])));
            aL[j] += sv;
            aH[j] += sw;
        }
    }
    if (p + 4 <= e) {
        int j0 = adj[p], j1 = adj[p + 1], j2 = adj[p + 2], j3 = adj[p + 3];
        const short* r0 = Xp + (size_t)j0 * 64 + quad * 8;
        const short* r1 = Xp + (size_t)j1 * 64 + quad * 8;
        const short* r2 = Xp + (size_t)j2 * 64 + quad * 8;
        const short* r3 = Xp + (size_t)j3 * 64 + quad * 8;
        s16x8 v0 = *(const s16x8*)r0, w0 = *(const s16x8*)(r0 + 32);
        s16x8 v1 = *(const s16x8*)r1, w1 = *(const s16x8*)(r1 + 32);
        s16x8 v2 = *(const s16x8*)r2, w2 = *(const s16x8*)(r2 + 32);
        s16x8 v3 = *(const s16x8*)r3, w3 = *(const s16x8*)(r3 + 32);
        #pragma unroll
        for (int j = 0; j < 8; j++) {
            aL[j] += (bs2f(v0[j]) + bs2f(v1[j])) + (bs2f(v2[j]) + bs2f(v3[j]));
            aH[j] += (bs2f(w0[j]) + bs2f(w1[j])) + (bs2f(w2[j]) + bs2f(w3[j]));
        }
        p += 4;
    }
    for (; p < e; p++) {
        int j0 = adj[p];
        const short* r0 = Xp + (size_t)j0 * 64 + quad * 8;
        s16x8 v0 = *(const s16x8*)r0, w0 = *(const s16x8*)(r0 + 32);
        #pragma unroll
        for (int j = 0; j < 8; j++) { aL[j] += bs2f(v0[j]); aH[j] += bs2f(w0[j]); }
    }

    s16x8 a0, a1;
    #pragma unroll
    for (int j = 0; j < 8; j++) { a0[j] = f2bs(aL[j]); a1[j] = f2bs(aH[j]); }

    f32x4 acc[4];
    #pragma unroll
    for (int nt = 0; nt < 4; nt++) {
        int n = nt * 16 + m;
        s16x8 b0 = *(const s16x8*)(Wt + n * 64 + quad * 8);
        s16x8 b1 = *(const s16x8*)(Wt + n * 64 + 32 + quad * 8);
        acc[nt] = (f32x4){0.f, 0.f, 0.f, 0.f};
        acc[nt] = __builtin_amdgcn_mfma_f32_16x16x32_bf16(a0, b0, acc[nt], 0, 0, 0);
        acc[nt] = __builtin_amdgcn_mfma_f32_16x16x32_bf16(a1, b1, acc[nt], 0, 0, 0);
    }
    #pragma unroll
    for (int nt = 0; nt < 4; nt++) {
        int col = nt * 16 + m;
        float bv = bias[col];
        float ps = 0.f, pq = 0.f;
        #pragma unroll
        for (int r = 0; r < 4; r++) {
            int orow = wrow + quad * 4 + r;
            if (orow < NN) {
                float v = acc[nt][r] + bv;
                __builtin_nontemporal_store(v, &T[(size_t)orow * 64 + col]);
                ps += v;
                pq += v * v;
            }
        }
        atomicAdd(&lsum[col], ps);
        atomicAdd(&lssq[col], pq);
    }
    __syncthreads();
    if (t < 64) {
        atomicAdd(&sums[t], lsum[t]);
        atomicAdd(&sums[64 + t], lssq[t]);
    }
}

// ---- GEMM with A = relu(bn(T)) built on the fly -> Tout fp32 + stats ----------
// T2 stores non-temporal as well (read later by bn_k/fin from L3) to keep L2
// for the layer-1 gather working set.
__global__ void gemm_bn_k(const float* __restrict__ Tin,
                          const float* __restrict__ stats,
                          const float* __restrict__ g, const float* __restrict__ be,
                          const short* __restrict__ Wt,    // 64x64 bf16 [n][k]
                          const float* __restrict__ bias,
                          float* __restrict__ T,
                          float* __restrict__ sums) {
    __shared__ float sc[64], sh[64], lsum[64], lssq[64];
    int tid = threadIdx.x;
    if (tid < 64) {
        float mm = stats[tid] * (1.0f / NN);
        float var = stats[64 + tid] * (1.0f / NN) - mm * mm;
        if (var < 0.f) var = 0.f;
        float s = g[tid] * rsqrtf(var + BN_EPS);
        sc[tid] = s;
        sh[tid] = be[tid] - mm * s;
        lsum[tid] = 0.f; lssq[tid] = 0.f;
    }
    __syncthreads();
    int wv = tid >> 6, L = tid & 63;
    int m = L & 15, quad = L >> 4;
    int wrow = blockIdx.x * 64 + wv * 16;
    int arow = wrow + m;
    if (arow >= NN) arow = NN - 1;
    f32x4 t0 = *(const f32x4*)(Tin + (size_t)arow * 64 + quad * 8);
    f32x4 t1 = *(const f32x4*)(Tin + (size_t)arow * 64 + quad * 8 + 4);
    f32x4 t2 = *(const f32x4*)(Tin + (size_t)arow * 64 + 32 + quad * 8);
    f32x4 t3 = *(const f32x4*)(Tin + (size_t)arow * 64 + 32 + quad * 8 + 4);
    s16x8 a0, a1;
    #pragma unroll
    for (int j = 0; j < 4; j++) {
        int k0 = quad * 8 + j, k1 = quad * 8 + 4 + j;
        float u0 = t0[j] * sc[k0] + sh[k0]; a0[j]     = f2bs(u0 > 0.f ? u0 : 0.f);
        float u1 = t1[j] * sc[k1] + sh[k1]; a0[4 + j] = f2bs(u1 > 0.f ? u1 : 0.f);
        float u2 = t2[j] * sc[32 + k0] + sh[32 + k0]; a1[j]     = f2bs(u2 > 0.f ? u2 : 0.f);
        float u3 = t3[j] * sc[32 + k1] + sh[32 + k1]; a1[4 + j] = f2bs(u3 > 0.f ? u3 : 0.f);
    }
    f32x4 acc[4];
    #pragma unroll
    for (int nt = 0; nt < 4; nt++) {
        int n = nt * 16 + m;
        s16x8 b0 = *(const s16x8*)(Wt + n * 64 + quad * 8);
        s16x8 b1 = *(const s16x8*)(Wt + n * 64 + 32 + quad * 8);
        acc[nt] = (f32x4){0.f, 0.f, 0.f, 0.f};
        acc[nt] = __builtin_amdgcn_mfma_f32_16x16x32_bf16(a0, b0, acc[nt], 0, 0, 0);
        acc[nt] = __builtin_amdgcn_mfma_f32_16x16x32_bf16(a1, b1, acc[nt], 0, 0, 0);
    }
    #pragma unroll
    for (int nt = 0; nt < 4; nt++) {
        int col = nt * 16 + m;
        float bv = bias[col];
        float ps = 0.f, pq = 0.f;
        #pragma unroll
        for (int r = 0; r < 4; r++) {
            int orow = wrow + quad * 4 + r;
            if (orow < NN) {
                float v = acc[nt][r] + bv;
                __builtin_nontemporal_store(v, &T[(size_t)orow * 64 + col]);
                ps += v;
                pq += v * v;
            }
        }
        atomicAdd(&lsum[col], ps);
        atomicAdd(&lssq[col], pq);
    }
    __syncthreads();
    if (tid < 64) {
        atomicAdd(&sums[tid], lsum[tid]);
        atomicAdd(&sums[64 + tid], lssq[tid]);
    }
}

// ---- BN finalize + apply + ReLU: T2 fp32 -> HCb bf16 --------------------------
__global__ void bn_k(const float* __restrict__ T, const float* __restrict__ sums,
                     const float* __restrict__ g, const float* __restrict__ be,
                     __hip_bfloat16* __restrict__ Hb) {
    __shared__ float sc[64], sh[64];
    int tid = threadIdx.x;
    if (tid < 64) {
        float m = sums[tid] * (1.0f / NN);
        float var = sums[64 + tid] * (1.0f / NN) - m * m;
        if (var < 0.f) var = 0.f;
        float s = g[tid] * rsqrtf(var + BN_EPS);
        sc[tid] = s;
        sh[tid] = be[tid] - m * s;
    }
    __syncthreads();
    int i = blockIdx.x * 256 + tid;  // over NN*16 float4s
    if (i < NN * 16) {
        int row = i >> 4, f = (i & 15) * 4;
        f32x4 v = *(const f32x4*)(T + (size_t)row * 64 + f);
        s16x4 ub;
        #pragma unroll
        for (int j = 0; j < 4; j++) {
            float w = v[j] * sc[f + j] + sh[f + j];
            ub[j] = f2bs(w > 0.f ? w : 0.f);
        }
        *(s16x4*)((short*)Hb + (size_t)row * 64 + f) = ub;
    }
}

// ---- final MFMA GEMM: [h1(bf16) | relu(bn(T2))] (Nx128) @ Wtf -> fp32 out -----
__global__ void gemm_fin_k(const __hip_bfloat16* __restrict__ H1b,
                           const float* __restrict__ T2,
                           const float* __restrict__ stats,
                           const float* __restrict__ g, const float* __restrict__ be,
                           const short* __restrict__ Wtf,   // [n][k], k=128, bf16
                           const float* __restrict__ bias,
                           float* __restrict__ O) {
    __shared__ float sc[64], sh[64];
    int tid = threadIdx.x;
    if (tid < 64) {
        float mm = stats[tid] * (1.0f / NN);
        float var = stats[64 + tid] * (1.0f / NN) - mm * mm;
        if (var < 0.f) var = 0.f;
        float s = g[tid] * rsqrtf(var + BN_EPS);
        sc[tid] = s;
        sh[tid] = be[tid] - mm * s;
    }
    __syncthreads();
    int wv = tid >> 6, L = tid & 63;
    int m = L & 15, quad = L >> 4;
    int wrow = blockIdx.x * 64 + wv * 16;
    int arow = wrow + m;
    if (arow >= NN) arow = NN - 1;
    const short* Hp = (const short*)H1b;
    s16x8 a0 = *(const s16x8*)(Hp + (size_t)arow * 64 + quad * 8);
    s16x8 a1 = *(const s16x8*)(Hp + (size_t)arow * 64 + 32 + quad * 8);
    f32x4 t0 = *(const f32x4*)(T2 + (size_t)arow * 64 + quad * 8);
    f32x4 t1 = *(const f32x4*)(T2 + (size_t)arow * 64 + quad * 8 + 4);
    f32x4 t2 = *(const f32x4*)(T2 + (size_t)arow * 64 + 32 + quad * 8);
    f32x4 t3 = *(const f32x4*)(T2 + (size_t)arow * 64 + 32 + quad * 8 + 4);
    s16x8 a2, a3;
    #pragma unroll
    for (int j = 0; j < 4; j++) {
        int k0 = quad * 8 + j, k1 = quad * 8 + 4 + j;
        float u0 = t0[j] * sc[k0] + sh[k0]; a2[j]     = f2bs(u0 > 0.f ? u0 : 0.f);
        float u1 = t1[j] * sc[k1] + sh[k1]; a2[4 + j] = f2bs(u1 > 0.f ? u1 : 0.f);
        float u2 = t2[j] * sc[32 + k0] + sh[32 + k0]; a3[j]     = f2bs(u2 > 0.f ? u2 : 0.f);
        float u3 = t3[j] * sc[32 + k1] + sh[32 + k1]; a3[4 + j] = f2bs(u3 > 0.f ? u3 : 0.f);
    }
    f32x4 acc[4];
    #pragma unroll
    for (int nt = 0; nt < 4; nt++) {
        int n = nt * 16 + m;
        s16x8 b0 = *(const s16x8*)(Wtf + n * 128 + quad * 8);
        s16x8 b1 = *(const s16x8*)(Wtf + n * 128 + 32 + quad * 8);
        s16x8 b2 = *(const s16x8*)(Wtf + n * 128 + 64 + quad * 8);
        s16x8 b3 = *(const s16x8*)(Wtf + n * 128 + 96 + quad * 8);
        acc[nt] = (f32x4){0.f, 0.f, 0.f, 0.f};
        acc[nt] = __builtin_amdgcn_mfma_f32_16x16x32_bf16(a0, b0, acc[nt], 0, 0, 0);
        acc[nt] = __builtin_amdgcn_mfma_f32_16x16x32_bf16(a1, b1, acc[nt], 0, 0, 0);
        acc[nt] = __builtin_amdgcn_mfma_f32_16x16x32_bf16(a2, b2, acc[nt], 0, 0, 0);
        acc[nt] = __builtin_amdgcn_mfma_f32_16x16x32_bf16(a3, b3, acc[nt], 0, 0, 0);
    }
    #pragma unroll
    for (int nt = 0; nt < 4; nt++) {
        int col = nt * 16 + m;
        float bv = bias[col];
        #pragma unroll
        for (int r = 0; r < 4; r++) {
            int orow = wrow + quad * 4 + r;
            if (orow < NN) {
                float v = acc[nt][r] + bv;
                __builtin_nontemporal_store(v, &O[(size_t)orow * 64 + col]);
            }
        }
    }
}

// ---------------- launch ----------------
extern "C" void kernel_launch(void* const* d_in, const int* in_sizes, int n_in,
                              void* d_out, int out_size, void* d_ws, size_t ws_size,
                              hipStream_t stream) {
    const float* x   = (const float*)d_in[0];
    const int*   ei  = (const int*)d_in[1];
    const float* w0a = (const float*)d_in[2];
    const float* b0a = (const float*)d_in[3];
    const float* g0a = (const float*)d_in[4];
    const float* be0a= (const float*)d_in[5];
    const float* w0b = (const float*)d_in[6];
    const float* b0b = (const float*)d_in[7];
    const float* g0b = (const float*)d_in[8];
    const float* be0b= (const float*)d_in[9];
    const float* w1a = (const float*)d_in[10];
    const float* b1a = (const float*)d_in[11];
    const float* g1a = (const float*)d_in[12];
    const float* be1a= (const float*)d_in[13];
    const float* w1b = (const float*)d_in[14];
    const float* b1b = (const float*)d_in[15];
    const float* g1b = (const float*)d_in[16];
    const float* be1b= (const float*)d_in[17];
    const float* lw  = (const float*)d_in[18];
    const float* lb  = (const float*)d_in[19];
    float* out = (float*)d_out;
    (void)in_sizes; (void)n_in; (void)out_size; (void)ws_size;

    char* wsb = (char*)d_ws;
    size_t o = 0;
    auto alloc = [&](size_t bytes) -> char* {
        char* p = wsb + o;
        o += (bytes + 255) & ~(size_t)255;
        return p;
    };
    int* part = (int*)alloc(NCH * 256 * 4);
    float* sums = (float*)alloc(512 * 4);
    int* bbase = (int*)alloc(257 * 4);
    int* bres = (int*)alloc(256 * 4);
    int* off = (int*)alloc((NN + 1) * 4);
    int* adj = (int*)alloc(NE * 4);
    int* ebuf = (int*)alloc(NE * 4);
    __hip_bfloat16* Xb  = (__hip_bfloat16*)alloc((size_t)NN * 64 * 2);
    __hip_bfloat16* HCb = (__hip_bfloat16*)alloc((size_t)NN * 64 * 2);
    float* T  = (float*)alloc((size_t)NN * 64 * 4);
    float* T2 = (float*)alloc((size_t)NN * 64 * 4);
    short* Wt0a = (short*)alloc(4096 * 2);
    short* Wt0b = (short*)alloc(4096 * 2);
    short* Wt1a = (short*)alloc(4096 * 2);
    short* Wt1b = (short*)alloc(4096 * 2);
    short* Wtf  = (short*)alloc(8192 * 2);

    const int* src = ei;
    const int* dst = ei + NE;

    prep_k<<<3326, 256, 0, stream>>>(dst, part, x, Xb, w0a, w0b, w1a, w1b, lw,
                                     Wt0a, Wt0b, Wt1a, Wt1b, Wtf);
    bscan_k<<<1, 256, 0, stream>>>(part, bbase, bres, off, sums);
    bscatter_k<<<NCH, 256, 0, stream>>>(src, dst, bres, ebuf);
    csr_k<<<NBK, 256, 0, stream>>>(bbase, ebuf, off, adj);

    const int mgrid = (NN + 63) / 64;          // 782
    const int agrid = (NN * 16 + 255) / 256;   // 3125

    // ---- layer 0 ----
    ggemm_k<<<mgrid, 256, 0, stream>>>(Xb, off, adj, Wt0a, b0a, T, sums + 0);
    gemm_bn_k<<<mgrid, 256, 0, stream>>>(T, sums + 0, g0a, be0a, Wt0b, b0b, T2, sums + 128);
    bn_k<<<agrid, 256, 0, stream>>>(T2, sums + 128, g0b, be0b, HCb);          // h1 bf16

    // ---- layer 1 ----
    ggemm_k<<<mgrid, 256, 0, stream>>>(HCb, off, adj, Wt1a, b1a, T, sums + 256);
    gemm_bn_k<<<mgrid, 256, 0, stream>>>(T, sums + 256, g1a, be1a, Wt1b, b1b, T2, sums + 384);

    // ---- JK cat + final linear (h2 BN fused; h1 read as bf16) ----
    gemm_fin_k<<<mgrid, 256, 0, stream>>>(HCb, T2, sums + 384, g1b, be1b, Wtf, lb, out);
}